// Round 2
// baseline (667.190 us; speedup 1.0000x reference)
//
#include <hip/hip_runtime.h>

// FractalDimension: out[row] = sum_{l=0}^{1023} in[row*1024 + l] / (l+1)
// rows = C*B*N = 131072, L = 1024, fp32 in/out.
// Memory-bound: 512 MB read @ ~6.3 TB/s -> ~81 us floor.
//
// R1 design: persistent waves. 2048 blocks x 256 thr (8 blocks/CU), one WAVE
// per row (no block barrier), 16 rows/wave. Per-lane denominators are
// row-invariant -> 16 precomputed reciprocals + FMA (no fp32 div sequence).

constexpr int kL = 1024;
constexpr int kBlocks = 2048;
constexpr int kThreads = 256;

__global__ __launch_bounds__(kThreads) void FractalDimension_kernel(
    const float* __restrict__ in, float* __restrict__ out, int rows) {
  const int lane = threadIdx.x & 63;
  const int waveId = blockIdx.x * (kThreads >> 6) + (threadIdx.x >> 6);
  const int nWaves = kBlocks * (kThreads >> 6);  // 8192

  // Reciprocals of this lane's 16 element positions (same for every row).
  float r[4][4];
#pragma unroll
  for (int k = 0; k < 4; ++k)
#pragma unroll
    for (int c = 0; c < 4; ++c)
      r[k][c] = 1.0f / (float)((lane + k * 64) * 4 + c + 1);

  const int trips = rows / nWaves;  // 16 for the target shape
#pragma unroll 2
  for (int i = 0; i < trips; ++i) {
    const int row = waveId + i * nWaves;
    const float4* p = reinterpret_cast<const float4*>(in + (size_t)row * kL);
    float4 v0 = p[lane];
    float4 v1 = p[lane + 64];
    float4 v2 = p[lane + 128];
    float4 v3 = p[lane + 192];

    float s = v0.x * r[0][0] + v0.y * r[0][1] + v0.z * r[0][2] + v0.w * r[0][3];
    s += v1.x * r[1][0] + v1.y * r[1][1] + v1.z * r[1][2] + v1.w * r[1][3];
    s += v2.x * r[2][0] + v2.y * r[2][1] + v2.z * r[2][2] + v2.w * r[2][3];
    s += v3.x * r[3][0] + v3.y * r[3][1] + v3.z * r[3][2] + v3.w * r[3][3];

    // Wave-64 butterfly reduce (LDS-pipe shuffles, no barrier).
#pragma unroll
    for (int off = 32; off > 0; off >>= 1)
      s += __shfl_down(s, off, 64);

    if (lane == 0) out[row] = s;
  }

  // Tail guard (not taken for 131072 rows / 8192 waves).
  for (int row = trips * nWaves + waveId; row < rows; row += nWaves) {
    const float4* p = reinterpret_cast<const float4*>(in + (size_t)row * kL);
    float s = 0.f;
#pragma unroll
    for (int k = 0; k < 4; ++k) {
      float4 v = p[lane + k * 64];
      s += v.x * r[k][0] + v.y * r[k][1] + v.z * r[k][2] + v.w * r[k][3];
    }
#pragma unroll
    for (int off = 32; off > 0; off >>= 1)
      s += __shfl_down(s, off, 64);
    if (lane == 0) out[row] = s;
  }
}

extern "C" void kernel_launch(void* const* d_in, const int* in_sizes, int n_in,
                              void* d_out, int out_size, void* d_ws, size_t ws_size,
                              hipStream_t stream) {
  const float* in = (const float*)d_in[0];
  float* out = (float*)d_out;
  const int rows = in_sizes[0] / kL;  // 131072
  FractalDimension_kernel<<<kBlocks, kThreads, 0, stream>>>(in, out, rows);
}